// Round 8
// baseline (596.242 us; speedup 1.0000x reference)
//
#include <hip/hip_runtime.h>
#include <hip/hip_bf16.h>
#include <math.h>

// ---------------- bucketed CSR build ----------------
// bucket = dst >> 8 (256 nodes/bucket). NB = ceil(N/256) <= 512.
// R6 post-mortem: single-pass random 4B scatter into csr caused 16x write
// amplification (105 MB HBM writes for a 6.4 MB array). Two-level counting
// sort keeps every write either block-grouped (pass A) or inside a 16 KB
// L2-hot bucket window (pass B).

#define CSR_CHUNK 8192

__global__ void k_bhist(const int* __restrict__ dst, int* __restrict__ bcount,
                        int E, int NB) {
    __shared__ int h[512];
    int t = threadIdx.x;
    for (int i = t; i < NB; i += 256) h[i] = 0;
    __syncthreads();
    int e0 = blockIdx.x * CSR_CHUNK;
    int e1 = min(e0 + CSR_CHUNK, E);
    for (int i = e0 + t; i < e1; i += 256) atomicAdd(&h[dst[i] >> 8], 1);
    __syncthreads();
    for (int i = t; i < NB; i += 256) {
        int c = h[i];
        if (c) atomicAdd(&bcount[i], c);
    }
}

// single block, 512 threads: exclusive scan of bcount -> bstart (NB+1), copy
// to gcur (mutable cursors), and set rowptr[N] = E.
__global__ void k_bscan(const int* __restrict__ bcount, int* __restrict__ bstart,
                        int* __restrict__ gcur, int* __restrict__ rowptr,
                        int NB, int N, int E) {
    __shared__ int s[512];
    int t = threadIdx.x;
    int v = (t < NB) ? bcount[t] : 0;
    s[t] = v;
    __syncthreads();
    for (int off = 1; off < 512; off <<= 1) {
        int a = (t >= off) ? s[t - off] : 0;
        __syncthreads();
        s[t] += a;
        __syncthreads();
    }
    int excl = s[t] - v;
    if (t < NB) {
        bstart[t] = excl;
        gcur[t] = excl;
    }
    if (t == 0) {
        bstart[NB] = E;
        rowptr[N] = E;
    }
}

// pass A: scatter packed edges grouped by bucket per block.
// pack: dstlocal(8) << 20 | rel(3) << 17 | src(17)
__global__ void k_bscatter(const int* __restrict__ src, const int* __restrict__ dst,
                           const int* __restrict__ et, int* __restrict__ gcur,
                           unsigned* __restrict__ ebuf, int E, int NB) {
    __shared__ int h[512];
    __shared__ int basearr[512];
    int t = threadIdx.x;
    for (int i = t; i < NB; i += 256) h[i] = 0;
    __syncthreads();
    int e0 = blockIdx.x * CSR_CHUNK;
    int e1 = min(e0 + CSR_CHUNK, E);
    for (int i = e0 + t; i < e1; i += 256) atomicAdd(&h[dst[i] >> 8], 1);
    __syncthreads();
    for (int i = t; i < NB; i += 256) {
        int c = h[i];
        basearr[i] = c ? atomicAdd(&gcur[i], c) : 0;
        h[i] = 0;
    }
    __syncthreads();
    for (int i = e0 + t; i < e1; i += 256) {
        int d = dst[i];
        int b = d >> 8;
        int off = atomicAdd(&h[b], 1);
        ebuf[basearr[b] + off] =
            ((unsigned)(d & 255) << 20) | ((unsigned)et[i] << 17) | (unsigned)src[i];
    }
}

// pass B: one block per bucket. Per-node counts -> rowptr; scatter csr entries
// (rel<<17|src) into the bucket's contiguous window.
__global__ void k_bsort(const unsigned* __restrict__ ebuf, const int* __restrict__ bstart,
                        int* __restrict__ rowptr, int* __restrict__ csr, int N) {
    __shared__ int lh[256];
    __shared__ int ls[256];
    __shared__ int ss[256];
    int b = blockIdx.x, t = threadIdx.x;
    int e0 = bstart[b], e1 = bstart[b + 1];
    lh[t] = 0;
    __syncthreads();
    for (int i = e0 + t; i < e1; i += 256) atomicAdd(&lh[(ebuf[i] >> 20) & 255], 1);
    __syncthreads();
    int v = lh[t];
    ss[t] = v;
    __syncthreads();
    for (int off = 1; off < 256; off <<= 1) {
        int a = (t >= off) ? ss[t - off] : 0;
        __syncthreads();
        ss[t] += a;
        __syncthreads();
    }
    ls[t] = ss[t] - v;  // exclusive scan
    int node = b * 256 + t;
    if (node < N) rowptr[node] = e0 + ls[t];
    lh[t] = 0;
    __syncthreads();
    for (int i = e0 + t; i < e1; i += 256) {
        unsigned u = ebuf[i];
        int d = (u >> 20) & 255;
        int off = atomicAdd(&lh[d], 1);
        csr[e0 + ls[d] + off] = (int)(u & 0xFFFFF);
    }
}

// ---------------- dtype prep ----------------

// fp32 -> bf16 (RNE), 4 elems/thread
__global__ void k_cast(const float4* __restrict__ in, ushort4* __restrict__ out, int n4) {
    int i = blockIdx.x * blockDim.x + threadIdx.x;
    if (i < n4) {
        float4 v = in[i];
        __hip_bfloat16 a = __float2bfloat16(v.x);
        __hip_bfloat16 b = __float2bfloat16(v.y);
        __hip_bfloat16 c = __float2bfloat16(v.z);
        __hip_bfloat16 d = __float2bfloat16(v.w);
        ushort4 o;
        o.x = *(unsigned short*)&a;
        o.y = *(unsigned short*)&b;
        o.z = *(unsigned short*)&c;
        o.w = *(unsigned short*)&d;
        out[i] = o;
    }
}

// ---------------- weight prep ----------------

// Split-transpose into GEMM-B layout with K = i*8 + r (matches z layout):
// wt[o][i*8+r] = bf16(W[r][i][o]); lo = bf16 residual. K=512 rows total.
__global__ void k_wt2(const float* __restrict__ W, __hip_bfloat16* __restrict__ hi,
                      __hip_bfloat16* __restrict__ lo, int OUT, int total) {
    int t = blockIdx.x * blockDim.x + threadIdx.x;
    if (t < total) {
        int per = 64 * OUT;
        int r = t / per;
        int rem = t % per;
        int i = rem / OUT;
        int o = rem % OUT;
        float v = W[t];
        __hip_bfloat16 h = __float2bfloat16(v);
        __hip_bfloat16 l = __float2bfloat16(v - __bfloat162float(h));
        size_t idx = (size_t)o * 512 + i * 8 + r;
        hi[idx] = h;
        lo[idx] = l;
    }
}

// wq[r*64+i] = sum_o W[r,i,o]*Qv[o]; wk likewise. (fp32, tiny)
__global__ void k_wqk(const float* W, const float* Qv, const float* Kv,
                      float* wq, float* wk, int OUT) {
    int t = blockIdx.x * blockDim.x + threadIdx.x;
    if (t < 8 * 64) {
        int r = t >> 6, i = t & 63;
        const float* wrow = W + ((size_t)r * 64 + i) * OUT;
        float a = 0.f, b = 0.f;
        for (int o = 0; o < OUT; o++) {
            float w = wrow[o];
            a += w * Qv[o];
            b += w * Kv[o];
        }
        wq[t] = a;
        wk[t] = b;
    }
}

// qn[n*8+r] = sum_i xin[n,i]*wq[r,i]; kn likewise. IN fixed at 64. (fp32)
__global__ void k_qk(const float* __restrict__ xin, const float* __restrict__ wq,
                     const float* __restrict__ wk, float* __restrict__ qn,
                     float* __restrict__ kn, int N) {
    __shared__ float sq[8 * 65], sk[8 * 65];
    int t = threadIdx.x;
    for (int idx = t; idx < 8 * 64; idx += blockDim.x) {
        int r = idx >> 6, i = idx & 63;
        sq[r * 65 + i] = wq[idx];
        sk[r * 65 + i] = wk[idx];
    }
    __syncthreads();
    int g = blockIdx.x * blockDim.x + t;
    if (g < N * 8) {
        int n = g >> 3, r = g & 7;
        const float* xp = xin + (size_t)n * 64;
        float qa = 0.f, ka = 0.f;
#pragma unroll
        for (int i = 0; i < 64; i++) {
            float xv = xp[i];
            qa += xv * sq[r * 65 + i];
            ka += xv * sk[r * 65 + i];
        }
        qn[g] = qa;
        kn[g] = ka;
    }
}

// ---------------- aggregation into per-relation z (bf16) ----------------
// One wave per dst node. Single-pass softmax (no max-sub; logits O(+-6)).
// z[n][ch*8 + r] = (1/denom) * sum_{e in rel r} exp(alpha_e) * xb[src_e][ch]
// R8: gather bf16 feature rows (128 B/edge vs 256) — k_agg2 was
// gather-bandwidth-bound (R7: FETCH 258 MB, 2.97 TB/s effective).
// Per-edge broadcast via v_readlane -> SGPRs; scalar src base -> saddr load.
// HAZARD (R3/R4): all cross-lane ops run with the FULL wave active.
__global__ void k_agg2(const int* __restrict__ rowptr, const int* __restrict__ csr,
                       const float* __restrict__ qn, const float* __restrict__ kn,
                       const unsigned short* __restrict__ xb,
                       __hip_bfloat16* __restrict__ z, int N) {
    int wid = (blockIdx.x * blockDim.x + threadIdx.x) >> 6;
    int lane = threadIdx.x & 63;
    if (wid >= N) return;
    int r0 = rowptr[wid], r1 = rowptr[wid + 1];

    float qv = (lane < 8) ? qn[wid * 8 + lane] : 0.f;

    float denom = 0.f;
    float a0 = 0.f, a1 = 0.f, a2 = 0.f, a3 = 0.f;
    float a4 = 0.f, a5 = 0.f, a6 = 0.f, a7 = 0.f;

    for (int base = r0; base < r1; base += 64) {
        int s = base + lane;
        int pk = (s < r1) ? csr[s] : 0;
        int src = pk & 0x1FFFF;
        int rel = pk >> 17;
        float q = __shfl(qv, rel, 64);  // full wave active here
        float tv = 0.f;
        if (s < r1) {
            float v = q + kn[src * 8 + rel];
            v = (v >= 0.f) ? v : 0.2f * v;
            tv = __expf(v);
        }
        float ts = tv;
#pragma unroll
        for (int off = 32; off > 0; off >>= 1) ts += __shfl_xor(ts, off, 64);
        denom += ts;
        int cnt = min(64, r1 - base);
        for (int j = 0; j < cnt; j++) {
            unsigned pkj = (unsigned)__builtin_amdgcn_readlane(pk, j);
            float tj = __uint_as_float(
                (unsigned)__builtin_amdgcn_readlane((int)__float_as_uint(tv), j));
            int srcj = (int)(pkj & 0x1FFFF);
            int relj = (int)(pkj >> 17);
            unsigned xu = (unsigned)xb[(size_t)srcj * 64 + lane];
            float xv = __uint_as_float(xu << 16);  // bf16 -> fp32
            switch (relj) {
                case 0: a0 += tj * xv; break;
                case 1: a1 += tj * xv; break;
                case 2: a2 += tj * xv; break;
                case 3: a3 += tj * xv; break;
                case 4: a4 += tj * xv; break;
                case 5: a5 += tj * xv; break;
                case 6: a6 += tj * xv; break;
                case 7: a7 += tj * xv; break;
            }
        }
    }

    float inv = 1.f / (denom + 1e-16f);
    unsigned short u[8];
    float av[8] = {a0, a1, a2, a3, a4, a5, a6, a7};
#pragma unroll
    for (int r = 0; r < 8; r++) {
        __hip_bfloat16 b = __float2bfloat16(av[r] * inv);
        u[r] = *(unsigned short*)&b;
    }
    uint4 pack;
    pack.x = (unsigned)u[0] | ((unsigned)u[1] << 16);
    pack.y = (unsigned)u[2] | ((unsigned)u[3] << 16);
    pack.z = (unsigned)u[4] | ((unsigned)u[5] << 16);
    pack.w = (unsigned)u[6] | ((unsigned)u[7] << 16);
    *(uint4*)((unsigned short*)z + (size_t)wid * 512 + lane * 8) = pack;
}

// ---------------- final transform: out = z . Wcat (+bias, relu) ----------------
// GEMM M=N, K=512, N=OUT via mfma_f32_16x16x32_bf16.
// Optionally also emits bf16 copy of the output (bout) for the next layer's
// bf16 gather.
template <int OUT, bool RELU>
__global__ __launch_bounds__(256) void k_zw(
        const __hip_bfloat16* __restrict__ z,
        const __hip_bfloat16* __restrict__ wthi, const __hip_bfloat16* __restrict__ wtlo,
        const float* __restrict__ bias, float* __restrict__ xout,
        unsigned short* __restrict__ bout, int N) {
    using v8s = __attribute__((ext_vector_type(8))) short;
    using v4f = __attribute__((ext_vector_type(4))) float;
    constexpr int NT = OUT / 16;
    int wave = threadIdx.x >> 6;
    int lane = threadIdx.x & 63;
    int quad = lane >> 4;
    int l15 = lane & 15;
    int m0 = (blockIdx.x * 4 + wave) * 32;
    if (m0 >= N) return;

    v4f acc[NT][2];
#pragma unroll
    for (int nt = 0; nt < NT; nt++) {
        acc[nt][0] = (v4f){0.f, 0.f, 0.f, 0.f};
        acc[nt][1] = (v4f){0.f, 0.f, 0.f, 0.f};
    }

    const short* zp = (const short*)z;
    const short* wh = (const short*)wthi;
    const short* wl = (const short*)wtlo;
    int n0 = m0 + l15, n1 = m0 + 16 + l15;

    for (int k0 = 0; k0 < 512; k0 += 32) {
        int koff = k0 + quad * 8;
        v8s A0 = {}, A1 = {};
        if (n0 < N) A0 = *(const v8s*)(zp + (size_t)n0 * 512 + koff);
        if (n1 < N) A1 = *(const v8s*)(zp + (size_t)n1 * 512 + koff);
#pragma unroll
        for (int nt = 0; nt < NT; nt++) {
            v8s bh = *(const v8s*)(wh + (size_t)(nt * 16 + l15) * 512 + koff);
            v8s bl = *(const v8s*)(wl + (size_t)(nt * 16 + l15) * 512 + koff);
            acc[nt][0] = __builtin_amdgcn_mfma_f32_16x16x32_bf16(A0, bh, acc[nt][0], 0, 0, 0);
            acc[nt][0] = __builtin_amdgcn_mfma_f32_16x16x32_bf16(A0, bl, acc[nt][0], 0, 0, 0);
            acc[nt][1] = __builtin_amdgcn_mfma_f32_16x16x32_bf16(A1, bh, acc[nt][1], 0, 0, 0);
            acc[nt][1] = __builtin_amdgcn_mfma_f32_16x16x32_bf16(A1, bl, acc[nt][1], 0, 0, 0);
        }
    }

#pragma unroll
    for (int nt = 0; nt < NT; nt++) {
        float bcol = bias[nt * 16 + l15];
#pragma unroll
        for (int mm = 0; mm < 2; mm++) {
#pragma unroll
            for (int g = 0; g < 4; g++) {
                int row = m0 + mm * 16 + quad * 4 + g;
                if (row < N) {
                    float o = acc[nt][mm][g] + bcol;
                    if (RELU) o = fmaxf(o, 0.f);
                    xout[(size_t)row * OUT + nt * 16 + l15] = o;
                    if (bout) {
                        __hip_bfloat16 ob = __float2bfloat16(o);
                        bout[(size_t)row * OUT + nt * 16 + l15] = *(unsigned short*)&ob;
                    }
                }
            }
        }
    }
}

// ---------------- host launch ----------------

extern "C" void kernel_launch(void* const* d_in, const int* in_sizes, int n_in,
                              void* d_out, int out_size, void* d_ws, size_t ws_size,
                              hipStream_t stream) {
    const float* x   = (const float*)d_in[0];
    const int*   ei  = (const int*)d_in[1];
    const int*   et  = (const int*)d_in[2];
    const float* W0  = (const float*)d_in[3];
    const float* Q0  = (const float*)d_in[4];
    const float* K0  = (const float*)d_in[5];
    const float* b0  = (const float*)d_in[6];
    const float* W1  = (const float*)d_in[7];
    const float* Q1  = (const float*)d_in[8];
    const float* K1  = (const float*)d_in[9];
    const float* b1  = (const float*)d_in[10];
    float* out = (float*)d_out;

    const int N = in_sizes[0] / 64;
    const int E = in_sizes[2];
    const int* src = ei;
    const int* dst = ei + E;
    const int NB = (N + 255) >> 8;  // <= 512

    char* p = (char*)d_ws;
    auto alloc = [&](size_t bytes) -> void* {
        void* r = (void*)p;
        p += ((bytes + 255) / 256) * 256;
        return r;
    };
    int* rowptr   = (int*)alloc((size_t)(N + 1) * 4);
    int* bcount   = (int*)alloc((size_t)NB * 4);
    int* bstart   = (int*)alloc((size_t)(NB + 1) * 4);
    int* gcur     = (int*)alloc((size_t)NB * 4);
    unsigned* ebuf = (unsigned*)alloc((size_t)E * 4);
    int* csr      = (int*)alloc((size_t)E * 4);
    float* wq     = (float*)alloc(8 * 64 * 4);
    float* wk     = (float*)alloc(8 * 64 * 4);
    float* qn     = (float*)alloc((size_t)N * 8 * 4);
    float* kn     = (float*)alloc((size_t)N * 8 * 4);
    __hip_bfloat16* wthi = (__hip_bfloat16*)alloc((size_t)64 * 512 * 2);
    __hip_bfloat16* wtlo = (__hip_bfloat16*)alloc((size_t)64 * 512 * 2);
    __hip_bfloat16* z    = (__hip_bfloat16*)alloc((size_t)N * 512 * 2);
    float* h      = (float*)alloc((size_t)N * 64 * 4);
    unsigned short* xbb = (unsigned short*)alloc((size_t)N * 64 * 2);  // bf16 gather table

    // --- CSR build (bucketed counting sort; shared by both layers) ---
    int nchunks = (E + CSR_CHUNK - 1) / CSR_CHUNK;
    hipMemsetAsync(bcount, 0, (size_t)NB * 4, stream);
    k_bhist<<<nchunks, 256, 0, stream>>>(dst, bcount, E, NB);
    k_bscan<<<1, 512, 0, stream>>>(bcount, bstart, gcur, rowptr, NB, N, E);
    k_bscatter<<<nchunks, 256, 0, stream>>>(src, dst, et, gcur, ebuf, E, NB);
    k_bsort<<<NB, 256, 0, stream>>>(ebuf, bstart, rowptr, csr, N);

    int naggb = (N * 64 + 255) / 256;
    int nzwb = (N + 127) / 128;
    int n4 = N * 64 / 4;

    // --- layer 0: 64 -> 64, relu ---
    k_wqk<<<2, 256, 0, stream>>>(W0, Q0, K0, wq, wk, 64);
    k_qk<<<(N * 8 + 255) / 256, 256, 0, stream>>>(x, wq, wk, qn, kn, N);
    k_cast<<<(n4 + 255) / 256, 256, 0, stream>>>((const float4*)x, (ushort4*)xbb, n4);
    k_wt2<<<(8 * 64 * 64 + 255) / 256, 256, 0, stream>>>(W0, wthi, wtlo, 64, 8 * 64 * 64);
    k_agg2<<<naggb, 256, 0, stream>>>(rowptr, csr, qn, kn, xbb, z, N);
    // emits fp32 h (for k_qk) + bf16 hb (reuses xbb; gather table for layer 1)
    k_zw<64, true><<<nzwb, 256, 0, stream>>>(z, wthi, wtlo, b0, h, xbb, N);

    // --- layer 1: 64 -> 32, no relu ---
    k_wqk<<<2, 256, 0, stream>>>(W1, Q1, K1, wq, wk, 32);
    k_qk<<<(N * 8 + 255) / 256, 256, 0, stream>>>(h, wq, wk, qn, kn, N);
    k_wt2<<<(8 * 64 * 32 + 255) / 256, 256, 0, stream>>>(W1, wthi, wtlo, 32, 8 * 64 * 32);
    k_agg2<<<naggb, 256, 0, stream>>>(rowptr, csr, qn, kn, xbb, z, N);
    k_zw<32, false><<<nzwb, 256, 0, stream>>>(z, wthi, wtlo, b1, out, nullptr, N);
}

// Round 9
// 500.971 us; speedup vs baseline: 1.1902x; 1.1902x over previous
//
#include <hip/hip_runtime.h>
#include <hip/hip_bf16.h>
#include <math.h>

// ---------------- bucketed CSR build ----------------
// bucket = dst >> 8 (256 nodes/bucket). NB = ceil(N/256) <= 512.
// R6 post-mortem: single-pass random 4B scatter into csr caused 16x write
// amplification. Two-level counting sort keeps every write either
// block-grouped (pass A) or inside a 16 KB L2-hot bucket window (pass B).

#define CSR_CHUNK 8192

__global__ void k_bhist(const int* __restrict__ dst, int* __restrict__ bcount,
                        int E, int NB) {
    __shared__ int h[512];
    int t = threadIdx.x;
    for (int i = t; i < NB; i += 256) h[i] = 0;
    __syncthreads();
    int e0 = blockIdx.x * CSR_CHUNK;
    int e1 = min(e0 + CSR_CHUNK, E);
    for (int i = e0 + t; i < e1; i += 256) atomicAdd(&h[dst[i] >> 8], 1);
    __syncthreads();
    for (int i = t; i < NB; i += 256) {
        int c = h[i];
        if (c) atomicAdd(&bcount[i], c);
    }
}

__global__ void k_bscan(const int* __restrict__ bcount, int* __restrict__ bstart,
                        int* __restrict__ gcur, int* __restrict__ rowptr,
                        int NB, int N, int E) {
    __shared__ int s[512];
    int t = threadIdx.x;
    int v = (t < NB) ? bcount[t] : 0;
    s[t] = v;
    __syncthreads();
    for (int off = 1; off < 512; off <<= 1) {
        int a = (t >= off) ? s[t - off] : 0;
        __syncthreads();
        s[t] += a;
        __syncthreads();
    }
    int excl = s[t] - v;
    if (t < NB) {
        bstart[t] = excl;
        gcur[t] = excl;
    }
    if (t == 0) {
        bstart[NB] = E;
        rowptr[N] = E;
    }
}

// pass A: scatter packed edges grouped by bucket per block.
// pack: dstlocal(8) << 20 | rel(3) << 17 | src(17)
__global__ void k_bscatter(const int* __restrict__ src, const int* __restrict__ dst,
                           const int* __restrict__ et, int* __restrict__ gcur,
                           unsigned* __restrict__ ebuf, int E, int NB) {
    __shared__ int h[512];
    __shared__ int basearr[512];
    int t = threadIdx.x;
    for (int i = t; i < NB; i += 256) h[i] = 0;
    __syncthreads();
    int e0 = blockIdx.x * CSR_CHUNK;
    int e1 = min(e0 + CSR_CHUNK, E);
    for (int i = e0 + t; i < e1; i += 256) atomicAdd(&h[dst[i] >> 8], 1);
    __syncthreads();
    for (int i = t; i < NB; i += 256) {
        int c = h[i];
        basearr[i] = c ? atomicAdd(&gcur[i], c) : 0;
        h[i] = 0;
    }
    __syncthreads();
    for (int i = e0 + t; i < e1; i += 256) {
        int d = dst[i];
        int b = d >> 8;
        int off = atomicAdd(&h[b], 1);
        ebuf[basearr[b] + off] =
            ((unsigned)(d & 255) << 20) | ((unsigned)et[i] << 17) | (unsigned)src[i];
    }
}

// pass B: one block per bucket. Per-node counts -> rowptr; scatter csr entries
// (rel<<17|src) into the bucket's contiguous window.
__global__ void k_bsort(const unsigned* __restrict__ ebuf, const int* __restrict__ bstart,
                        int* __restrict__ rowptr, int* __restrict__ csr, int N) {
    __shared__ int lh[256];
    __shared__ int ls[256];
    __shared__ int ss[256];
    int b = blockIdx.x, t = threadIdx.x;
    int e0 = bstart[b], e1 = bstart[b + 1];
    lh[t] = 0;
    __syncthreads();
    for (int i = e0 + t; i < e1; i += 256) atomicAdd(&lh[(ebuf[i] >> 20) & 255], 1);
    __syncthreads();
    int v = lh[t];
    ss[t] = v;
    __syncthreads();
    for (int off = 1; off < 256; off <<= 1) {
        int a = (t >= off) ? ss[t - off] : 0;
        __syncthreads();
        ss[t] += a;
        __syncthreads();
    }
    ls[t] = ss[t] - v;  // exclusive scan
    int node = b * 256 + t;
    if (node < N) rowptr[node] = e0 + ls[t];
    lh[t] = 0;
    __syncthreads();
    for (int i = e0 + t; i < e1; i += 256) {
        unsigned u = ebuf[i];
        int d = (u >> 20) & 255;
        int off = atomicAdd(&lh[d], 1);
        csr[e0 + ls[d] + off] = (int)(u & 0xFFFFF);
    }
}

// ---------------- dtype prep ----------------

__global__ void k_cast(const float4* __restrict__ in, ushort4* __restrict__ out, int n4) {
    int i = blockIdx.x * blockDim.x + threadIdx.x;
    if (i < n4) {
        float4 v = in[i];
        __hip_bfloat16 a = __float2bfloat16(v.x);
        __hip_bfloat16 b = __float2bfloat16(v.y);
        __hip_bfloat16 c = __float2bfloat16(v.z);
        __hip_bfloat16 d = __float2bfloat16(v.w);
        ushort4 o;
        o.x = *(unsigned short*)&a;
        o.y = *(unsigned short*)&b;
        o.z = *(unsigned short*)&c;
        o.w = *(unsigned short*)&d;
        out[i] = o;
    }
}

// ---------------- weight prep ----------------

// Split-transpose into GEMM-B layout with K = i*8 + r (matches z layout):
// wt[o][i*8+r] = bf16(W[r][i][o]); lo = bf16 residual. K=512 rows total.
__global__ void k_wt2(const float* __restrict__ W, __hip_bfloat16* __restrict__ hi,
                      __hip_bfloat16* __restrict__ lo, int OUT, int total) {
    int t = blockIdx.x * blockDim.x + threadIdx.x;
    if (t < total) {
        int per = 64 * OUT;
        int r = t / per;
        int rem = t % per;
        int i = rem / OUT;
        int o = rem % OUT;
        float v = W[t];
        __hip_bfloat16 h = __float2bfloat16(v);
        __hip_bfloat16 l = __float2bfloat16(v - __bfloat162float(h));
        size_t idx = (size_t)o * 512 + i * 8 + r;
        hi[idx] = h;
        lo[idx] = l;
    }
}

// wq[r*64+i] = sum_o W[r,i,o]*Qv[o]; wk likewise. (fp32, tiny)
__global__ void k_wqk(const float* W, const float* Qv, const float* Kv,
                      float* wq, float* wk, int OUT) {
    int t = blockIdx.x * blockDim.x + threadIdx.x;
    if (t < 8 * 64) {
        int r = t >> 6, i = t & 63;
        const float* wrow = W + ((size_t)r * 64 + i) * OUT;
        float a = 0.f, b = 0.f;
        for (int o = 0; o < OUT; o++) {
            float w = wrow[o];
            a += w * Qv[o];
            b += w * Kv[o];
        }
        wq[t] = a;
        wk[t] = b;
    }
}

// qn[n*8+r] = sum_i xin[n,i]*wq[r,i]; kn likewise. IN fixed at 64. (fp32)
__global__ void k_qk(const float* __restrict__ xin, const float* __restrict__ wq,
                     const float* __restrict__ wk, float* __restrict__ qn,
                     float* __restrict__ kn, int N) {
    __shared__ float sq[8 * 65], sk[8 * 65];
    int t = threadIdx.x;
    for (int idx = t; idx < 8 * 64; idx += blockDim.x) {
        int r = idx >> 6, i = idx & 63;
        sq[r * 65 + i] = wq[idx];
        sk[r * 65 + i] = wk[idx];
    }
    __syncthreads();
    int g = blockIdx.x * blockDim.x + t;
    if (g < N * 8) {
        int n = g >> 3, r = g & 7;
        const float* xp = xin + (size_t)n * 64;
        float qa = 0.f, ka = 0.f;
#pragma unroll
        for (int i = 0; i < 64; i++) {
            float xv = xp[i];
            qa += xv * sq[r * 65 + i];
            ka += xv * sk[r * 65 + i];
        }
        qn[g] = qa;
        kn[g] = ka;
    }
}

// ---------------- aggregation into per-relation z (bf16) ----------------
// One wave per dst node. Single-pass softmax (no max-sub; logits O(+-6)).
// z[n][ch*8 + r] = (1/denom) * sum_{e in rel r} exp(alpha_e) * xb[src_e][ch]
// R9: j-loop unrolled x8 with BATCHED loads. R8 proved the kernel is
// MLP-bound (FETCH halved, dur unchanged): the per-edge load was issued
// inside the serial readlane->switch chain, so <=2 gathers in flight/wave.
// Batching 8 independent row-loads in straight-line code before the 8
// switch+FMA blocks raises MLP ~8x. Tail slots carry pk=0,tv=0 ->
// harmless row-0 load + FMA of zero (no tail logic needed).
// HAZARD (R3/R4): all cross-lane ops run with the FULL wave active.
__global__ void k_agg2(const int* __restrict__ rowptr, const int* __restrict__ csr,
                       const float* __restrict__ qn, const float* __restrict__ kn,
                       const unsigned short* __restrict__ xb,
                       __hip_bfloat16* __restrict__ z, int N) {
    int wid = (blockIdx.x * blockDim.x + threadIdx.x) >> 6;
    int lane = threadIdx.x & 63;
    if (wid >= N) return;
    int r0 = rowptr[wid], r1 = rowptr[wid + 1];

    float qv = (lane < 8) ? qn[wid * 8 + lane] : 0.f;

    float denom = 0.f;
    float a0 = 0.f, a1 = 0.f, a2 = 0.f, a3 = 0.f;
    float a4 = 0.f, a5 = 0.f, a6 = 0.f, a7 = 0.f;

    for (int base = r0; base < r1; base += 64) {
        int s = base + lane;
        int pk = (s < r1) ? csr[s] : 0;
        int src = pk & 0x1FFFF;
        int rel = pk >> 17;
        float q = __shfl(qv, rel, 64);  // full wave active here
        float tv = 0.f;
        if (s < r1) {
            float v = q + kn[src * 8 + rel];
            v = (v >= 0.f) ? v : 0.2f * v;
            tv = __expf(v);
        }
        float ts = tv;
#pragma unroll
        for (int off = 32; off > 0; off >>= 1) ts += __shfl_xor(ts, off, 64);
        denom += ts;

        int cnt = min(64, r1 - base);
        int tvi = (int)__float_as_uint(tv);
        for (int j = 0; j < cnt; j += 8) {
            // broadcast 8 edges' metadata to SGPRs
            unsigned p[8];
            float t[8];
#pragma unroll
            for (int u = 0; u < 8; u++) {
                p[u] = (unsigned)__builtin_amdgcn_readlane(pk, j + u);
                t[u] = __uint_as_float((unsigned)__builtin_amdgcn_readlane(tvi, j + u));
            }
            // 8 independent gathers, issued back-to-back (no branches between)
            unsigned xu[8];
#pragma unroll
            for (int u = 0; u < 8; u++)
                xu[u] = (unsigned)xb[(size_t)(p[u] & 0x1FFFF) * 64 + lane];
            // accumulate (scalar switch per edge; loads already in flight)
#pragma unroll
            for (int u = 0; u < 8; u++) {
                float xv = __uint_as_float(xu[u] << 16);
                float tj = t[u];
                switch (p[u] >> 17) {
                    case 0: a0 += tj * xv; break;
                    case 1: a1 += tj * xv; break;
                    case 2: a2 += tj * xv; break;
                    case 3: a3 += tj * xv; break;
                    case 4: a4 += tj * xv; break;
                    case 5: a5 += tj * xv; break;
                    case 6: a6 += tj * xv; break;
                    case 7: a7 += tj * xv; break;
                }
            }
        }
    }

    float inv = 1.f / (denom + 1e-16f);
    unsigned short u[8];
    float av[8] = {a0, a1, a2, a3, a4, a5, a6, a7};
#pragma unroll
    for (int r = 0; r < 8; r++) {
        __hip_bfloat16 b = __float2bfloat16(av[r] * inv);
        u[r] = *(unsigned short*)&b;
    }
    uint4 pack;
    pack.x = (unsigned)u[0] | ((unsigned)u[1] << 16);
    pack.y = (unsigned)u[2] | ((unsigned)u[3] << 16);
    pack.z = (unsigned)u[4] | ((unsigned)u[5] << 16);
    pack.w = (unsigned)u[6] | ((unsigned)u[7] << 16);
    *(uint4*)((unsigned short*)z + (size_t)wid * 512 + lane * 8) = pack;
}

// ---------------- final transform: out = z . Wcat (+bias, relu) ----------------
// GEMM M=N, K=512, N=OUT via mfma_f32_16x16x32_bf16.
// Optionally also emits bf16 copy of the output (bout) for the next layer's
// bf16 gather.
template <int OUT, bool RELU>
__global__ __launch_bounds__(256) void k_zw(
        const __hip_bfloat16* __restrict__ z,
        const __hip_bfloat16* __restrict__ wthi, const __hip_bfloat16* __restrict__ wtlo,
        const float* __restrict__ bias, float* __restrict__ xout,
        unsigned short* __restrict__ bout, int N) {
    using v8s = __attribute__((ext_vector_type(8))) short;
    using v4f = __attribute__((ext_vector_type(4))) float;
    constexpr int NT = OUT / 16;
    int wave = threadIdx.x >> 6;
    int lane = threadIdx.x & 63;
    int quad = lane >> 4;
    int l15 = lane & 15;
    int m0 = (blockIdx.x * 4 + wave) * 32;
    if (m0 >= N) return;

    v4f acc[NT][2];
#pragma unroll
    for (int nt = 0; nt < NT; nt++) {
        acc[nt][0] = (v4f){0.f, 0.f, 0.f, 0.f};
        acc[nt][1] = (v4f){0.f, 0.f, 0.f, 0.f};
    }

    const short* zp = (const short*)z;
    const short* wh = (const short*)wthi;
    const short* wl = (const short*)wtlo;
    int n0 = m0 + l15, n1 = m0 + 16 + l15;

    for (int k0 = 0; k0 < 512; k0 += 32) {
        int koff = k0 + quad * 8;
        v8s A0 = {}, A1 = {};
        if (n0 < N) A0 = *(const v8s*)(zp + (size_t)n0 * 512 + koff);
        if (n1 < N) A1 = *(const v8s*)(zp + (size_t)n1 * 512 + koff);
#pragma unroll
        for (int nt = 0; nt < NT; nt++) {
            v8s bh = *(const v8s*)(wh + (size_t)(nt * 16 + l15) * 512 + koff);
            v8s bl = *(const v8s*)(wl + (size_t)(nt * 16 + l15) * 512 + koff);
            acc[nt][0] = __builtin_amdgcn_mfma_f32_16x16x32_bf16(A0, bh, acc[nt][0], 0, 0, 0);
            acc[nt][0] = __builtin_amdgcn_mfma_f32_16x16x32_bf16(A0, bl, acc[nt][0], 0, 0, 0);
            acc[nt][1] = __builtin_amdgcn_mfma_f32_16x16x32_bf16(A1, bh, acc[nt][1], 0, 0, 0);
            acc[nt][1] = __builtin_amdgcn_mfma_f32_16x16x32_bf16(A1, bl, acc[nt][1], 0, 0, 0);
        }
    }

#pragma unroll
    for (int nt = 0; nt < NT; nt++) {
        float bcol = bias[nt * 16 + l15];
#pragma unroll
        for (int mm = 0; mm < 2; mm++) {
#pragma unroll
            for (int g = 0; g < 4; g++) {
                int row = m0 + mm * 16 + quad * 4 + g;
                if (row < N) {
                    float o = acc[nt][mm][g] + bcol;
                    if (RELU) o = fmaxf(o, 0.f);
                    xout[(size_t)row * OUT + nt * 16 + l15] = o;
                    if (bout) {
                        __hip_bfloat16 ob = __float2bfloat16(o);
                        bout[(size_t)row * OUT + nt * 16 + l15] = *(unsigned short*)&ob;
                    }
                }
            }
        }
    }
}

// ---------------- host launch ----------------

extern "C" void kernel_launch(void* const* d_in, const int* in_sizes, int n_in,
                              void* d_out, int out_size, void* d_ws, size_t ws_size,
                              hipStream_t stream) {
    const float* x   = (const float*)d_in[0];
    const int*   ei  = (const int*)d_in[1];
    const int*   et  = (const int*)d_in[2];
    const float* W0  = (const float*)d_in[3];
    const float* Q0  = (const float*)d_in[4];
    const float* K0  = (const float*)d_in[5];
    const float* b0  = (const float*)d_in[6];
    const float* W1  = (const float*)d_in[7];
    const float* Q1  = (const float*)d_in[8];
    const float* K1  = (const float*)d_in[9];
    const float* b1  = (const float*)d_in[10];
    float* out = (float*)d_out;

    const int N = in_sizes[0] / 64;
    const int E = in_sizes[2];
    const int* src = ei;
    const int* dst = ei + E;
    const int NB = (N + 255) >> 8;  // <= 512

    char* p = (char*)d_ws;
    auto alloc = [&](size_t bytes) -> void* {
        void* r = (void*)p;
        p += ((bytes + 255) / 256) * 256;
        return r;
    };
    int* rowptr   = (int*)alloc((size_t)(N + 1) * 4);
    int* bcount   = (int*)alloc((size_t)NB * 4);
    int* bstart   = (int*)alloc((size_t)(NB + 1) * 4);
    int* gcur     = (int*)alloc((size_t)NB * 4);
    unsigned* ebuf = (unsigned*)alloc((size_t)E * 4);
    int* csr      = (int*)alloc((size_t)E * 4);
    float* wq     = (float*)alloc(8 * 64 * 4);
    float* wk     = (float*)alloc(8 * 64 * 4);
    float* qn     = (float*)alloc((size_t)N * 8 * 4);
    float* kn     = (float*)alloc((size_t)N * 8 * 4);
    __hip_bfloat16* wthi = (__hip_bfloat16*)alloc((size_t)64 * 512 * 2);
    __hip_bfloat16* wtlo = (__hip_bfloat16*)alloc((size_t)64 * 512 * 2);
    __hip_bfloat16* z    = (__hip_bfloat16*)alloc((size_t)N * 512 * 2);
    float* h      = (float*)alloc((size_t)N * 64 * 4);
    unsigned short* xbb = (unsigned short*)alloc((size_t)N * 64 * 2);  // bf16 gather table

    // --- CSR build (bucketed counting sort; shared by both layers) ---
    int nchunks = (E + CSR_CHUNK - 1) / CSR_CHUNK;
    hipMemsetAsync(bcount, 0, (size_t)NB * 4, stream);
    k_bhist<<<nchunks, 256, 0, stream>>>(dst, bcount, E, NB);
    k_bscan<<<1, 512, 0, stream>>>(bcount, bstart, gcur, rowptr, NB, N, E);
    k_bscatter<<<nchunks, 256, 0, stream>>>(src, dst, et, gcur, ebuf, E, NB);
    k_bsort<<<NB, 256, 0, stream>>>(ebuf, bstart, rowptr, csr, N);

    int naggb = (N * 64 + 255) / 256;
    int nzwb = (N + 127) / 128;
    int n4 = N * 64 / 4;

    // --- layer 0: 64 -> 64, relu ---
    k_wqk<<<2, 256, 0, stream>>>(W0, Q0, K0, wq, wk, 64);
    k_qk<<<(N * 8 + 255) / 256, 256, 0, stream>>>(x, wq, wk, qn, kn, N);
    k_cast<<<(n4 + 255) / 256, 256, 0, stream>>>((const float4*)x, (ushort4*)xbb, n4);
    k_wt2<<<(8 * 64 * 64 + 255) / 256, 256, 0, stream>>>(W0, wthi, wtlo, 64, 8 * 64 * 64);
    k_agg2<<<naggb, 256, 0, stream>>>(rowptr, csr, qn, kn, xbb, z, N);
    // emits fp32 h (for k_qk) + bf16 hb (reuses xbb; gather table for layer 1)
    k_zw<64, true><<<nzwb, 256, 0, stream>>>(z, wthi, wtlo, b0, h, xbb, N);

    // --- layer 1: 64 -> 32, no relu ---
    k_wqk<<<2, 256, 0, stream>>>(W1, Q1, K1, wq, wk, 32);
    k_qk<<<(N * 8 + 255) / 256, 256, 0, stream>>>(h, wq, wk, qn, kn, N);
    k_wt2<<<(8 * 64 * 32 + 255) / 256, 256, 0, stream>>>(W1, wthi, wtlo, 32, 8 * 64 * 32);
    k_agg2<<<naggb, 256, 0, stream>>>(rowptr, csr, qn, kn, xbb, z, N);
    k_zw<32, false><<<nzwb, 256, 0, stream>>>(z, wthi, wtlo, b1, out, nullptr, N);
}